// Round 1
// baseline (428.748 us; speedup 1.0000x reference)
//
#include <hip/hip_runtime.h>
#include <math.h>

// Problem constants: B=32768, L=2, D=1024, DK=1
constexpr int D_DIM = 1024;
constexpr float INV_SQRT_D = 0.03125f;  // 1/sqrt(1024)

// One wave (64 lanes) per batch element.
// lane l owns float4 chunks {l, l+64, l+128, l+192} of each 1024-float row.
__global__ __launch_bounds__(256) void attn_collapse_kernel(
    const float* __restrict__ X,   // (B, 2, D)
    const float* __restrict__ W,   // (D,) since DK=1
    float* __restrict__ Y,         // (B, 2, D)
    int B) {
  const int gthread = blockIdx.x * blockDim.x + threadIdx.x;
  const int wave = gthread >> 6;
  const int lane = threadIdx.x & 63;
  if (wave >= B) return;

  const float* x0base = X + (size_t)wave * (2 * D_DIM);
  const float* x1base = x0base + D_DIM;

  float4 x0[4], x1[4];
  float d0 = 0.f, d1 = 0.f, ws = 0.f;

#pragma unroll
  for (int k = 0; k < 4; ++k) {
    const int idx = (lane + (k << 6)) << 2;  // float offset, 16B-aligned
    const float4 w = *(const float4*)(W + idx);
    x0[k] = *(const float4*)(x0base + idx);
    x1[k] = *(const float4*)(x1base + idx);
    d0 += x0[k].x * w.x + x0[k].y * w.y + x0[k].z * w.z + x0[k].w * w.w;
    d1 += x1[k].x * w.x + x1[k].y * w.y + x1[k].z * w.z + x1[k].w * w.w;
    ws += w.x + w.y + w.z + w.w;
  }

  // Butterfly reduce across the 64-lane wave.
#pragma unroll
  for (int off = 32; off > 0; off >>= 1) {
    d0 += __shfl_xor(d0, off, 64);
    d1 += __shfl_xor(d1, off, 64);
    ws += __shfl_xor(ws, off, 64);
  }

  // q0 = dot(X0 + 1/32, W) / 32 ; q1 = dot(X1 - 1/32, W) / 32
  const float q0 = (d0 + ws * INV_SQRT_D) * INV_SQRT_D;
  const float q1 = (d1 - ws * INV_SQRT_D) * INV_SQRT_D;
  const float dq = q0 - q1;
  // softmax of [[q0q0, q0q1],[q1q0, q1q1]] rows -> sigmoids of row-diffs
  const float a00 = 1.f / (1.f + __expf(-(q0 * dq)));
  const float a10 = 1.f / (1.f + __expf(-(q1 * dq)));
  const float b00 = 1.f - a00;
  const float b10 = 1.f - a10;

  float* y0 = Y + (size_t)wave * (2 * D_DIM);
  float* y1 = y0 + D_DIM;

#pragma unroll
  for (int k = 0; k < 4; ++k) {
    const int idx = (lane + (k << 6)) << 2;
    // positional offsets: row0 +1/32, row1 -1/32
    float4 p0, p1, o0, o1;
    p0.x = x0[k].x + INV_SQRT_D; p0.y = x0[k].y + INV_SQRT_D;
    p0.z = x0[k].z + INV_SQRT_D; p0.w = x0[k].w + INV_SQRT_D;
    p1.x = x1[k].x - INV_SQRT_D; p1.y = x1[k].y - INV_SQRT_D;
    p1.z = x1[k].z - INV_SQRT_D; p1.w = x1[k].w - INV_SQRT_D;

    o0.x = a00 * p0.x + b00 * p1.x;
    o0.y = a00 * p0.y + b00 * p1.y;
    o0.z = a00 * p0.z + b00 * p1.z;
    o0.w = a00 * p0.w + b00 * p1.w;
    o1.x = a10 * p0.x + b10 * p1.x;
    o1.y = a10 * p0.y + b10 * p1.y;
    o1.z = a10 * p0.z + b10 * p1.z;
    o1.w = a10 * p0.w + b10 * p1.w;

    *(float4*)(y0 + idx) = o0;
    *(float4*)(y1 + idx) = o1;
  }
}

extern "C" void kernel_launch(void* const* d_in, const int* in_sizes, int n_in,
                              void* d_out, int out_size, void* d_ws, size_t ws_size,
                              hipStream_t stream) {
  const float* X = (const float*)d_in[0];
  const float* W = (const float*)d_in[1];
  float* Y = (float*)d_out;

  const int B = in_sizes[0] / (2 * D_DIM);  // 32768

  const int waves_per_block = 4;            // 256 threads
  const int blocks = (B + waves_per_block - 1) / waves_per_block;
  attn_collapse_kernel<<<blocks, 256, 0, stream>>>(X, W, Y, B);
}